// Round 1
// baseline (160.774 us; speedup 1.0000x reference)
//
#include <hip/hip_runtime.h>
#include <hip/hip_bf16.h>

// EdgePredictor: out[e] = relu(concat(X[row], X[col]) @ W1 + b1) @ W2 + b2
// Precompute per-node AB[n][256] = {X[n]@W1[:128,:] | X[n]@W1[128:,:]} in f16.
// Per edge: out = relu(A[row] + B[col] + b1) @ W2 + b2.
//
// R10 (edge_mlp latency attack): counters showed edge_mlp latency-bound
// (Occ 36%, VGPR=52 => compiler sank gathers to ~8 in flight, HBM 32%,
// FETCH 120MB vs 51MB AB => LLC retains only ~half of AB). Changes:
// (1) persistent grid-stride edge_mlp, 1280 blocks, index prefetch one
//     group ahead; __launch_bounds__(256,4) so all 16 gathers stay in
//     flight (64 VGPRs of load destinations).
// (2) nontemporal X loads in gemm_ab + nontemporal eidx/out in edge_mlp
//     so AB is the only hot LLC resident -> gather misses become LLC hits.

#define EMBED 128

typedef _Float16 half8 __attribute__((ext_vector_type(8)));
typedef _Float16 half4 __attribute__((ext_vector_type(4)));
typedef float floatx4 __attribute__((ext_vector_type(4)));

// --- Kernel 0: fused prep.
// Blocks 0..127: transpose+convert W1 (256x128 f32) -> WT (256x128 f16),
//   WT[j][k] = Wcat[k][j] (Wcat = [W1 top | W1 bottom] per concat split).
// Block 128: idx-mode ballot detect; W2PT[16][128] f16; b1f[128] f16.
__global__ __launch_bounds__(256) void prep(
    const float* __restrict__ W1, const float* __restrict__ W2,
    const float* __restrict__ b1, const int* __restrict__ idx,
    _Float16* __restrict__ WT, _Float16* __restrict__ W2PT,
    _Float16* __restrict__ b1f, int* __restrict__ flag) {
    if (blockIdx.x < 128) {
        __shared__ float lds[16][17];
        const int ty = threadIdx.x >> 4, tx = threadIdx.x & 15;
        const int r0 = (blockIdx.x >> 3) * 16;   // source W1 row tile
        const int c0 = (blockIdx.x & 7) * 16;    // source W1 col tile
        lds[ty][tx] = W1[(r0 + ty) * 128 + c0 + tx];
        __syncthreads();
        const int jbase = c0 + (r0 >= 128 ? 128 : 0);
        const int kbase = r0 & 127;
        WT[(size_t)(jbase + ty) * 128 + kbase + tx] = (_Float16)lds[tx][ty];
    } else {
        const int t = threadIdx.x;
        if (t < 64) {  // int64 layout iff first 64 high words are all zero
            const int hw = idx[2 * t + 1];
            const unsigned long long m = __ballot(hw != 0);
            if (t == 0) *flag = (m == 0ull) ? 1 : 0;
        }
        if (t < 128) b1f[t] = (_Float16)b1[t];
        for (int i = t; i < 2048; i += 256) {  // W2PT[n][k] = n<2 ? W2[k][n] : 0
            const int n = i >> 7, k = i & 127;
            W2PT[i] = (n < 2) ? (_Float16)W2[k * 2 + n] : (_Float16)0.f;
        }
    }
}

// --- Kernel 1: AB = [X | X] @ Wcat via f16 MFMA, operand-swapped
// (A-operand = W-frag so D rows are output cols). Grid-stride, 2 tiles per
// block; next tile's X loads prefetched into registers during compute.
// X loads are NONTEMPORAL: X is read exactly once; keep it out of the LLC
// so AB (written here, randomly gathered by edge_mlp) stays resident.
__global__ __launch_bounds__(256) void gemm_ab(
    const float* __restrict__ X, const _Float16* __restrict__ WT,
    _Float16* __restrict__ AB, int n_nodes, int n_tiles) {
    __shared__ _Float16 sh[64 * 264];  // 33792 B union: xs(17408) / outs(33792)
    _Float16* xs   = sh;               // stride 136
    _Float16* outs = sh;               // stride 264
    const int t = threadIdx.x;
    const int w = t >> 6, lane = t & 63, lm = lane & 15, quad = lane >> 4;

    // Per-thread stage coordinates (fixed across tiles).
    int srow[8], scol[8];
#pragma unroll
    for (int i = 0; i < 8; ++i) {
        const int flat = i * 1024 + t * 4;
        srow[i] = flat >> 7;
        scol[i] = flat & 127;
    }

    int T = blockIdx.x;
    floatx4 pf[8];
    if (T < n_tiles) {  // prefetch first tile
#pragma unroll
        for (int i = 0; i < 8; ++i) {
            int node = T * 64 + srow[i];
            if (node > n_nodes - 1) node = n_nodes - 1;  // clamp; never stored
            pf[i] = __builtin_nontemporal_load(
                (const floatx4*)(X + (size_t)node * EMBED + scol[i]));
        }
    }

    for (; T < n_tiles; T += gridDim.x) {
        const int mblk = T * 64;

        // Stage: spill prefetched registers to LDS (convert f32->f16 once).
#pragma unroll
        for (int i = 0; i < 8; ++i) {
            half4 h;
            h[0] = (_Float16)pf[i][0]; h[1] = (_Float16)pf[i][1];
            h[2] = (_Float16)pf[i][2]; h[3] = (_Float16)pf[i][3];
            *(half4*)(xs + srow[i] * 136 + scol[i]) = h;
        }
        __syncthreads();  // S1: stage visible

        // Prefetch next tile NOW — loads overlap this tile's MFMA+epilogue.
        const int Tn = T + gridDim.x;
        if (Tn < n_tiles) {
#pragma unroll
            for (int i = 0; i < 8; ++i) {
                int node = Tn * 64 + srow[i];
                if (node > n_nodes - 1) node = n_nodes - 1;
                pf[i] = __builtin_nontemporal_load(
                    (const floatx4*)(X + (size_t)node * EMBED + scol[i]));
            }
        }

        floatx4 acc[4][4];  // [mf: node tile][jf: col tile]
#pragma unroll
        for (int a = 0; a < 4; ++a)
#pragma unroll
            for (int b = 0; b < 4; ++b)
                acc[a][b] = (floatx4){0.f, 0.f, 0.f, 0.f};

#pragma unroll
        for (int ks = 0; ks < 4; ++ks) {
            const int k0 = ks * 32 + quad * 8;
            half8 xf[4];  // B-operand: B[k][n=lane&15] = Xf16[node mf*16+lm][k]
#pragma unroll
            for (int mf = 0; mf < 4; ++mf)
                xf[mf] = *(const half8*)(xs + (mf * 16 + lm) * 136 + k0);
#pragma unroll
            for (int jf = 0; jf < 4; ++jf) {
                const int j = w * 64 + jf * 16 + lm;  // A-op: WT row = out col
                const half8 wf = *(const half8*)(WT + (size_t)j * EMBED + k0);
#pragma unroll
                for (int mf = 0; mf < 4; ++mf)
                    acc[mf][jf] = __builtin_amdgcn_mfma_f32_16x16x32_f16(wf, xf[mf], acc[mf][jf], 0, 0, 0);
            }
        }
        __syncthreads();  // S2: xs reads done before outs overwrites union

        // Pack D into LDS out tile: node-major [local node][j], stride 264.
        // D: col(lane&15) = node within mf-tile, row(quad*4+r) = output col j.
#pragma unroll
        for (int mf = 0; mf < 4; ++mf) {
#pragma unroll
            for (int jf = 0; jf < 4; ++jf) {
                half4 h;
#pragma unroll
                for (int r = 0; r < 4; ++r) h[r] = (_Float16)acc[mf][jf][r];
                *(half4*)(outs + (mf * 16 + lm) * 264 + w * 64 + jf * 16 + quad * 4) = h;
            }
        }
        __syncthreads();  // S3: outs visible

        // Coalesced store: 64 nodes x 512 B contiguous in AB (node-major).
#pragma unroll
        for (int i = 0; i < 8; ++i) {
            const int idx8 = i * 256 + t;         // half8 index in 64x256 tile
            const int node = idx8 >> 5, jj = idx8 & 31;
            if (mblk + node < n_nodes)
                *(half8*)(AB + (size_t)(mblk + node) * 256 + jj * 8) =
                    *(const half8*)(outs + node * 264 + jj * 8);
        }
        __syncthreads();  // S4: outs reads done before next tile's stage
    }
}

// --- Kernel 2: per-edge MLP, persistent grid-stride, 32 edges/wave per
// group. All 16 gathers for the current group issue before any use
// (launch_bounds(256,4) => 128-VGPR budget so the compiler keeps them in
// flight); the NEXT group's 4 index loads issue while gathers fly.
// eidx loads and out stores are nontemporal (streamed once) to keep the
// LLC dedicated to AB.
__global__ __launch_bounds__(256, 4) void edge_mlp(
    const _Float16* __restrict__ AB, const int* __restrict__ eidx,
    const int* __restrict__ flag, const _Float16* __restrict__ b1f,
    const _Float16* __restrict__ W2PT, const float* __restrict__ b2,
    float* __restrict__ out, int n_edges) {
    const int lane = threadIdx.x & 63, lm = lane & 15, quad = lane >> 4;
    const int W = gridDim.x * 4;               // total waves
    const int G = (n_edges + 31) / 32;         // 32-edge groups
    int g = blockIdx.x * 4 + (threadIdx.x >> 6);
    if (g >= G) return;

    const int mode = *flag;  // wave-uniform
    const float b2v = b2[lm & 1];  // only used when lm<2

    // Loop-invariant W2 fragment (per-lane): hoisted out of the group loop.
    half8 wv[4];
#pragma unroll
    for (int ks = 0; ks < 4; ++ks)
        wv[ks] = *(const half8*)(W2PT + lm * 128 + ks * 32 + quad * 8);

    auto load_idx = [&](int gg, int& r0, int& c0, int& r1, int& c1) {
        int e0 = gg * 32 + lm, e1 = gg * 32 + 16 + lm;
        if (e0 > n_edges - 1) e0 = n_edges - 1;  // clamp; stores guarded
        if (e1 > n_edges - 1) e1 = n_edges - 1;
        if (mode) {  // int64 layout: low word at int32 index 2*k
            r0 = __builtin_nontemporal_load(eidx + 2 * (size_t)e0);
            c0 = __builtin_nontemporal_load(eidx + 2 * ((size_t)n_edges + e0));
            r1 = __builtin_nontemporal_load(eidx + 2 * (size_t)e1);
            c1 = __builtin_nontemporal_load(eidx + 2 * ((size_t)n_edges + e1));
        } else {
            r0 = __builtin_nontemporal_load(eidx + e0);
            c0 = __builtin_nontemporal_load(eidx + (size_t)n_edges + e0);
            r1 = __builtin_nontemporal_load(eidx + e1);
            c1 = __builtin_nontemporal_load(eidx + (size_t)n_edges + e1);
        }
    };

    int row0, col0, row1, col1;
    load_idx(g, row0, col0, row1, col1);

    for (;;) {
        // Issue all 16 gathers for this group (each b128: 16 edges x 64B line).
        const _Float16* a0p = AB + (size_t)row0 * 256;
        const _Float16* b0p = AB + (size_t)col0 * 256 + 128;
        const _Float16* a1p = AB + (size_t)row1 * 256;
        const _Float16* c1p = AB + (size_t)col1 * 256 + 128;
        half8 a0[4], b0[4], a1[4], c1[4];
#pragma unroll
        for (int ks = 0; ks < 4; ++ks) {
            const int k0 = ks * 32 + quad * 8;
            a0[ks] = *(const half8*)(a0p + k0);
            b0[ks] = *(const half8*)(b0p + k0);
            a1[ks] = *(const half8*)(a1p + k0);
            c1[ks] = *(const half8*)(c1p + k0);
        }

        // Prefetch NEXT group's indices while the gathers are in flight.
        const int gn = g + W;
        int nr0 = 0, nc0 = 0, nr1 = 0, nc1 = 0;
        if (gn < G) load_idx(gn, nr0, nc0, nr1, nc1);

        floatx4 acc0 = (floatx4){0.f, 0.f, 0.f, 0.f};
        floatx4 acc1 = (floatx4){0.f, 0.f, 0.f, 0.f};
#pragma unroll
        for (int ks = 0; ks < 4; ++ks) {
            const int k0 = ks * 32 + quad * 8;
            const half8 bi = *(const half8*)(b1f + k0);  // L1-hot, wave-uniform
            half8 h0 = a0[ks] + b0[ks] + bi;
            half8 h1 = a1[ks] + c1[ks] + bi;
#pragma unroll
            for (int j = 0; j < 8; ++j) {
                h0[j] = h0[j] > (_Float16)0.f ? h0[j] : (_Float16)0.f;
                h1[j] = h1[j] > (_Float16)0.f ? h1[j] : (_Float16)0.f;
            }
            acc0 = __builtin_amdgcn_mfma_f32_16x16x32_f16(h0, wv[ks], acc0, 0, 0, 0);
            acc1 = __builtin_amdgcn_mfma_f32_16x16x32_f16(h1, wv[ks], acc1, 0, 0, 0);
        }

        if (lm < 2) {
            const int ebase = g * 32;
#pragma unroll
            for (int r = 0; r < 4; ++r) {
                const int ed0 = ebase + quad * 4 + r;
                const int ed1 = ebase + 16 + quad * 4 + r;
                if (ed0 < n_edges)
                    __builtin_nontemporal_store(acc0[r] + b2v, out + (size_t)ed0 * 2 + lm);
                if (ed1 < n_edges)
                    __builtin_nontemporal_store(acc1[r] + b2v, out + (size_t)ed1 * 2 + lm);
            }
        }

        if (gn >= G) break;
        g = gn;
        row0 = nr0; col0 = nc0; row1 = nr1; col1 = nc1;
    }
}

extern "C" void kernel_launch(void* const* d_in, const int* in_sizes, int n_in,
                              void* d_out, int out_size, void* d_ws, size_t ws_size,
                              hipStream_t stream) {
    const float* X   = (const float*)d_in[0];
    const int*   idx = (const int*)d_in[1];
    const float* W1  = (const float*)d_in[2];
    const float* b1  = (const float*)d_in[3];
    const float* W2  = (const float*)d_in[4];
    const float* b2  = (const float*)d_in[5];
    float* out = (float*)d_out;

    const int n_nodes = in_sizes[0] / EMBED;   // 100000
    const int n_edges = in_sizes[1] / 2;       // 500000

    // ws: flag @0 | AB @256 (n_nodes*256*2 B) | WT (64KB) | W2PT (4KB) | b1f (256B)
    char* ws = (char*)d_ws;
    int*      flag = (int*)ws;
    _Float16* AB   = (_Float16*)(ws + 256);
    _Float16* WT   = (_Float16*)(ws + 256 + (size_t)n_nodes * 512);
    _Float16* W2PT = WT + 256 * 128;
    _Float16* b1f  = W2PT + 16 * 128;

    const int n_tiles = (n_nodes + 63) / 64;   // 1563

    prep<<<129, 256, 0, stream>>>(W1, W2, b1, idx, WT, W2PT, b1f, flag);
    gemm_ab<<<782, 256, 0, stream>>>(X, WT, AB, n_nodes, n_tiles);
    edge_mlp<<<1280, 256, 0, stream>>>(
        AB, idx, flag, b1f, W2PT, b2, out, n_edges);
}

// Round 2
// 147.145 us; speedup vs baseline: 1.0926x; 1.0926x over previous
//
#include <hip/hip_runtime.h>
#include <hip/hip_bf16.h>

// EdgePredictor: out[e] = relu(concat(X[row], X[col]) @ W1 + b1) @ W2 + b2
// Precompute per-node AB[n][256] = {X[n]@W1[:128,:] | X[n]@W1[128:,:]} in f16.
// Per edge: out = relu(A[row] + B[col] + b1) @ W2 + b2.
//
// R11: (a) revert gemm_ab nontemporal X loads (R10: cost ~9us; nt was
// null-to-negative everywhere, FETCH unchanged). (b) edge_mlp rebuilt as a
// 2-deep explicitly software-pipelined gather loop: 16 edges/wave/group,
// 8 b128 gathers per group in TWO register sets; while group g computes,
// group g+1's gathers and group g+2's indices are in flight. Issue order
// (idx BEFORE gathers) makes in-order vmcnt completion give counted waits
// (vmcnt(10)), never a full drain in steady state. Theory: both prior
// rounds sat at ~2.7 TB/s miss-path with ~2 lines/wave in flight
// (compiler-sunk loads); per-wave MLP is the untested variable.

#define EMBED 128

typedef _Float16 half8 __attribute__((ext_vector_type(8)));
typedef _Float16 half4 __attribute__((ext_vector_type(4)));
typedef float floatx4 __attribute__((ext_vector_type(4)));

// --- Kernel 0: fused prep.
// Blocks 0..127: transpose+convert W1 (256x128 f32) -> WT (256x128 f16),
//   WT[j][k] = Wcat[k][j] (Wcat = [W1 top | W1 bottom] per concat split).
// Block 128: idx-mode ballot detect; W2PT[16][128] f16; b1f[128] f16.
__global__ __launch_bounds__(256) void prep(
    const float* __restrict__ W1, const float* __restrict__ W2,
    const float* __restrict__ b1, const int* __restrict__ idx,
    _Float16* __restrict__ WT, _Float16* __restrict__ W2PT,
    _Float16* __restrict__ b1f, int* __restrict__ flag) {
    if (blockIdx.x < 128) {
        __shared__ float lds[16][17];
        const int ty = threadIdx.x >> 4, tx = threadIdx.x & 15;
        const int r0 = (blockIdx.x >> 3) * 16;   // source W1 row tile
        const int c0 = (blockIdx.x & 7) * 16;    // source W1 col tile
        lds[ty][tx] = W1[(r0 + ty) * 128 + c0 + tx];
        __syncthreads();
        const int jbase = c0 + (r0 >= 128 ? 128 : 0);
        const int kbase = r0 & 127;
        WT[(size_t)(jbase + ty) * 128 + kbase + tx] = (_Float16)lds[tx][ty];
    } else {
        const int t = threadIdx.x;
        if (t < 64) {  // int64 layout iff first 64 high words are all zero
            const int hw = idx[2 * t + 1];
            const unsigned long long m = __ballot(hw != 0);
            if (t == 0) *flag = (m == 0ull) ? 1 : 0;
        }
        if (t < 128) b1f[t] = (_Float16)b1[t];
        for (int i = t; i < 2048; i += 256) {  // W2PT[n][k] = n<2 ? W2[k][n] : 0
            const int n = i >> 7, k = i & 127;
            W2PT[i] = (n < 2) ? (_Float16)W2[k * 2 + n] : (_Float16)0.f;
        }
    }
}

// --- Kernel 1: AB = [X | X] @ Wcat via f16 MFMA, operand-swapped
// (A-operand = W-frag so D rows are output cols). Grid-stride, 2 tiles per
// block; next tile's X loads prefetched into registers during compute.
// (R11: plain float4 X loads — nontemporal regressed ~9us in R10.)
__global__ __launch_bounds__(256) void gemm_ab(
    const float* __restrict__ X, const _Float16* __restrict__ WT,
    _Float16* __restrict__ AB, int n_nodes, int n_tiles) {
    __shared__ _Float16 sh[64 * 264];  // 33792 B union: xs(17408) / outs(33792)
    _Float16* xs   = sh;               // stride 136
    _Float16* outs = sh;               // stride 264
    const int t = threadIdx.x;
    const int w = t >> 6, lane = t & 63, lm = lane & 15, quad = lane >> 4;

    // Per-thread stage coordinates (fixed across tiles).
    int srow[8], scol[8];
#pragma unroll
    for (int i = 0; i < 8; ++i) {
        const int flat = i * 1024 + t * 4;
        srow[i] = flat >> 7;
        scol[i] = flat & 127;
    }

    int T = blockIdx.x;
    float4 pf[8];
    if (T < n_tiles) {  // prefetch first tile
#pragma unroll
        for (int i = 0; i < 8; ++i) {
            int node = T * 64 + srow[i];
            if (node > n_nodes - 1) node = n_nodes - 1;  // clamp; never stored
            pf[i] = *(const float4*)(X + (size_t)node * EMBED + scol[i]);
        }
    }

    for (; T < n_tiles; T += gridDim.x) {
        const int mblk = T * 64;

        // Stage: spill prefetched registers to LDS (convert f32->f16 once).
#pragma unroll
        for (int i = 0; i < 8; ++i) {
            half4 h;
            h[0] = (_Float16)pf[i].x; h[1] = (_Float16)pf[i].y;
            h[2] = (_Float16)pf[i].z; h[3] = (_Float16)pf[i].w;
            *(half4*)(xs + srow[i] * 136 + scol[i]) = h;
        }
        __syncthreads();  // S1: stage visible

        // Prefetch next tile NOW — loads overlap this tile's MFMA+epilogue.
        const int Tn = T + gridDim.x;
        if (Tn < n_tiles) {
#pragma unroll
            for (int i = 0; i < 8; ++i) {
                int node = Tn * 64 + srow[i];
                if (node > n_nodes - 1) node = n_nodes - 1;
                pf[i] = *(const float4*)(X + (size_t)node * EMBED + scol[i]);
            }
        }

        floatx4 acc[4][4];  // [mf: node tile][jf: col tile]
#pragma unroll
        for (int a = 0; a < 4; ++a)
#pragma unroll
            for (int b = 0; b < 4; ++b)
                acc[a][b] = (floatx4){0.f, 0.f, 0.f, 0.f};

#pragma unroll
        for (int ks = 0; ks < 4; ++ks) {
            const int k0 = ks * 32 + quad * 8;
            half8 xf[4];  // B-operand: B[k][n=lane&15] = Xf16[node mf*16+lm][k]
#pragma unroll
            for (int mf = 0; mf < 4; ++mf)
                xf[mf] = *(const half8*)(xs + (mf * 16 + lm) * 136 + k0);
#pragma unroll
            for (int jf = 0; jf < 4; ++jf) {
                const int j = w * 64 + jf * 16 + lm;  // A-op: WT row = out col
                const half8 wf = *(const half8*)(WT + (size_t)j * EMBED + k0);
#pragma unroll
                for (int mf = 0; mf < 4; ++mf)
                    acc[mf][jf] = __builtin_amdgcn_mfma_f32_16x16x32_f16(wf, xf[mf], acc[mf][jf], 0, 0, 0);
            }
        }
        __syncthreads();  // S2: xs reads done before outs overwrites union

        // Pack D into LDS out tile: node-major [local node][j], stride 264.
        // D: col(lane&15) = node within mf-tile, row(quad*4+r) = output col j.
#pragma unroll
        for (int mf = 0; mf < 4; ++mf) {
#pragma unroll
            for (int jf = 0; jf < 4; ++jf) {
                half4 h;
#pragma unroll
                for (int r = 0; r < 4; ++r) h[r] = (_Float16)acc[mf][jf][r];
                *(half4*)(outs + (mf * 16 + lm) * 264 + w * 64 + jf * 16 + quad * 4) = h;
            }
        }
        __syncthreads();  // S3: outs visible

        // Coalesced store: 64 nodes x 512 B contiguous in AB (node-major).
#pragma unroll
        for (int i = 0; i < 8; ++i) {
            const int idx8 = i * 256 + t;         // half8 index in 64x256 tile
            const int node = idx8 >> 5, jj = idx8 & 31;
            if (mblk + node < n_nodes)
                *(half8*)(AB + (size_t)(mblk + node) * 256 + jj * 8) =
                    *(const half8*)(outs + node * 264 + jj * 8);
        }
        __syncthreads();  // S4: outs reads done before next tile's stage
    }
}

// --- Kernel 2: per-edge MLP. 16 edges per wave-group, persistent waves,
// 2-deep software pipeline: while computing group g (register set A),
// group g+1's 8 gathers (set B) and group g+2's indices are in flight.
// Issue order per phase: idx(g+2) first, then gathers(g+1), then compute(g)
// — so in-order vmcnt completion yields counted waits (vmcnt(10)), never a
// full drain in steady state. b1f/W2PT/b2 hoisted to registers so the
// loop's only VMEM ops are the pipelined idx loads, gathers, and stores.
__global__ __launch_bounds__(256, 3) void edge_mlp(
    const _Float16* __restrict__ AB, const int* __restrict__ eidx,
    const int* __restrict__ flag, const _Float16* __restrict__ b1f,
    const _Float16* __restrict__ W2PT, const float* __restrict__ b2,
    float* __restrict__ out, int n_edges) {
    const int lane = threadIdx.x & 63, lm = lane & 15, quad = lane >> 4;
    const int W = gridDim.x * 4;               // total waves
    const int G = (n_edges + 15) / 16;         // 16-edge groups
    const int wid = blockIdx.x * 4 + (threadIdx.x >> 6);
    if (wid >= G) return;

    const int mode = *flag;        // wave-uniform
    const float b2v = b2[lm & 1];  // only used when lm<2

    // Loop-invariant operands in registers (kept out of the vmcnt stream).
    half8 wv[4], bv[4];
#pragma unroll
    for (int ks = 0; ks < 4; ++ks) {
        wv[ks] = *(const half8*)(W2PT + lm * 128 + ks * 32 + quad * 8);
        bv[ks] = *(const half8*)(b1f + ks * 32 + quad * 8);
    }

    // Lane lm serves edge g*16+lm (quads replicate -> broadcast loads).
    auto ldidx = [&](int g, int& r, int& c) {
        int e = g * 16 + lm;
        if (e > n_edges - 1) e = n_edges - 1;  // tail clamp; stores guarded
        if (mode) {  // int64 layout: low word at int32 index 2*k
            r = eidx[2 * (size_t)e];
            c = eidx[2 * ((size_t)n_edges + e)];
        } else {
            r = eidx[e];
            c = eidx[(size_t)n_edges + e];
        }
    };

    // Issue the 8 gathers for one group (each b128: 16 edges x one 64B line).
    auto gather = [&](int r, int c, half8* d) {
        const _Float16* ap = AB + (size_t)r * 256;
        const _Float16* bp = AB + (size_t)c * 256 + 128;
#pragma unroll
        for (int ks = 0; ks < 4; ++ks) {
            const int k0 = ks * 32 + quad * 8;
            d[ks]     = *(const half8*)(ap + k0);
            d[ks + 4] = *(const half8*)(bp + k0);
        }
    };

    auto comp = [&](int g, const half8* d) {
        floatx4 acc = (floatx4){0.f, 0.f, 0.f, 0.f};
#pragma unroll
        for (int ks = 0; ks < 4; ++ks) {
            half8 h = d[ks] + d[ks + 4] + bv[ks];
#pragma unroll
            for (int j = 0; j < 8; ++j)
                h[j] = h[j] > (_Float16)0.f ? h[j] : (_Float16)0.f;
            acc = __builtin_amdgcn_mfma_f32_16x16x32_f16(h, wv[ks], acc, 0, 0, 0);
        }
        if (lm < 2) {
            const int eb = g * 16;
#pragma unroll
            for (int r = 0; r < 4; ++r) {
                const int ed = eb + quad * 4 + r;
                if (ed < n_edges) out[(size_t)ed * 2 + lm] = acc[r] + b2v;
            }
        }
    };

    // ---- pipeline prologue ----
    int g0 = wid;
    int g1 = g0 + W;
    bool h1 = g1 < G;
    int r0, c0, r1, c1;
    ldidx(g0, r0, c0);                 // 2 vm
    if (h1) ldidx(g1, r1, c1);         // 2 vm (after idx0 -> wait idx0 = vmcnt(2))
    half8 a0[8], a1[8];
    gather(r0, c0, a0);                // 8 vm in flight for g0

    // ---- steady state: two phases per iteration, static register names ----
    for (;;) {
        // Phase 0: set a0 outstanding for g0; idx(g1) in regs.
        const int g2 = g1 + W;
        const bool h2 = h1 && (g2 < G);
        if (h1) {
            if (h2) ldidx(g2, r0, c0);  // reuse r0/c0 regs for g2
            gather(r1, c1, a1);         // wait idx(g1) = vmcnt(10); a0 stays out
        }
        comp(g0, a0);                   // wait a0 = vmcnt(10); a1+idx(g2) out
        if (!h1) break;

        // Phase 1: roles swapped — a1 outstanding for g1; idx(g2) in regs.
        const int g3 = g2 + W;
        const bool h3 = h2 && (g3 < G);
        if (h2) {
            if (h3) ldidx(g3, r1, c1);
            gather(r0, c0, a0);         // wait idx(g2) = vmcnt(10)
        }
        comp(g1, a1);                   // wait a1 = vmcnt(10)
        if (!h2) break;

        g0 = g2; g1 = g3; h1 = h3;
    }
}

extern "C" void kernel_launch(void* const* d_in, const int* in_sizes, int n_in,
                              void* d_out, int out_size, void* d_ws, size_t ws_size,
                              hipStream_t stream) {
    const float* X   = (const float*)d_in[0];
    const int*   idx = (const int*)d_in[1];
    const float* W1  = (const float*)d_in[2];
    const float* b1  = (const float*)d_in[3];
    const float* W2  = (const float*)d_in[4];
    const float* b2  = (const float*)d_in[5];
    float* out = (float*)d_out;

    const int n_nodes = in_sizes[0] / EMBED;   // 100000
    const int n_edges = in_sizes[1] / 2;       // 500000

    // ws: flag @0 | AB @256 (n_nodes*256*2 B) | WT (64KB) | W2PT (4KB) | b1f (256B)
    char* ws = (char*)d_ws;
    int*      flag = (int*)ws;
    _Float16* AB   = (_Float16*)(ws + 256);
    _Float16* WT   = (_Float16*)(ws + 256 + (size_t)n_nodes * 512);
    _Float16* W2PT = WT + 256 * 128;
    _Float16* b1f  = W2PT + 16 * 128;

    const int n_tiles = (n_nodes + 63) / 64;   // 1563

    prep<<<129, 256, 0, stream>>>(W1, W2, b1, idx, WT, W2PT, b1f, flag);
    gemm_ab<<<782, 256, 0, stream>>>(X, WT, AB, n_nodes, n_tiles);
    // 768 persistent blocks = 3 blocks/CU x 4 waves = 12 waves/CU at the
    // (256,3) VGPR cap; ~10 groups/wave keeps the 2-deep pipeline filled.
    edge_mlp<<<768, 256, 0, stream>>>(
        AB, idx, flag, b1f, W2PT, b2, out, n_edges);
}

// Round 3
// 146.419 us; speedup vs baseline: 1.0980x; 1.0050x over previous
//
#include <hip/hip_runtime.h>
#include <hip/hip_bf16.h>

// EdgePredictor: out[e] = relu(concat(X[row], X[col]) @ W1 + b1) @ W2 + b2
// Precompute per-node AB[n][256] = {X[n]@W1[:128,:] | X[n]@W1[128:,:]} in f16.
// Per edge: out = relu(A[row] + B[col] + b1) @ W2 + b2.
//
// R12: R11's 2-deep pipeline never materialized — VGPR=64 proves the
// compiler sank gather(a1) below comp(a0)'s reads (two live sets need
// >=96 regs). Fix: pin with __builtin_amdgcn_sched_barrier(0) after each
// pipeline-stage issue so all 8 of the next group's gathers are emitted
// before the current group's first use. Expect VGPR ~130, edge ~31us.
// (Harness note: the two 42us/256MiB fillBufferAligned dispatches are
// workspace re-poison — fixed cost, not ours.)

#define EMBED 128

typedef _Float16 half8 __attribute__((ext_vector_type(8)));
typedef _Float16 half4 __attribute__((ext_vector_type(4)));
typedef float floatx4 __attribute__((ext_vector_type(4)));

// --- Kernel 0: fused prep.
// Blocks 0..127: transpose+convert W1 (256x128 f32) -> WT (256x128 f16),
//   WT[j][k] = Wcat[k][j] (Wcat = [W1 top | W1 bottom] per concat split).
// Block 128: idx-mode ballot detect; W2PT[16][128] f16; b1f[128] f16.
__global__ __launch_bounds__(256) void prep(
    const float* __restrict__ W1, const float* __restrict__ W2,
    const float* __restrict__ b1, const int* __restrict__ idx,
    _Float16* __restrict__ WT, _Float16* __restrict__ W2PT,
    _Float16* __restrict__ b1f, int* __restrict__ flag) {
    if (blockIdx.x < 128) {
        __shared__ float lds[16][17];
        const int ty = threadIdx.x >> 4, tx = threadIdx.x & 15;
        const int r0 = (blockIdx.x >> 3) * 16;   // source W1 row tile
        const int c0 = (blockIdx.x & 7) * 16;    // source W1 col tile
        lds[ty][tx] = W1[(r0 + ty) * 128 + c0 + tx];
        __syncthreads();
        const int jbase = c0 + (r0 >= 128 ? 128 : 0);
        const int kbase = r0 & 127;
        WT[(size_t)(jbase + ty) * 128 + kbase + tx] = (_Float16)lds[tx][ty];
    } else {
        const int t = threadIdx.x;
        if (t < 64) {  // int64 layout iff first 64 high words are all zero
            const int hw = idx[2 * t + 1];
            const unsigned long long m = __ballot(hw != 0);
            if (t == 0) *flag = (m == 0ull) ? 1 : 0;
        }
        if (t < 128) b1f[t] = (_Float16)b1[t];
        for (int i = t; i < 2048; i += 256) {  // W2PT[n][k] = n<2 ? W2[k][n] : 0
            const int n = i >> 7, k = i & 127;
            W2PT[i] = (n < 2) ? (_Float16)W2[k * 2 + n] : (_Float16)0.f;
        }
    }
}

// --- Kernel 1: AB = [X | X] @ Wcat via f16 MFMA, operand-swapped
// (A-operand = W-frag so D rows are output cols). Grid-stride, 2 tiles per
// block; next tile's X loads prefetched into registers during compute.
__global__ __launch_bounds__(256) void gemm_ab(
    const float* __restrict__ X, const _Float16* __restrict__ WT,
    _Float16* __restrict__ AB, int n_nodes, int n_tiles) {
    __shared__ _Float16 sh[64 * 264];  // 33792 B union: xs(17408) / outs(33792)
    _Float16* xs   = sh;               // stride 136
    _Float16* outs = sh;               // stride 264
    const int t = threadIdx.x;
    const int w = t >> 6, lane = t & 63, lm = lane & 15, quad = lane >> 4;

    // Per-thread stage coordinates (fixed across tiles).
    int srow[8], scol[8];
#pragma unroll
    for (int i = 0; i < 8; ++i) {
        const int flat = i * 1024 + t * 4;
        srow[i] = flat >> 7;
        scol[i] = flat & 127;
    }

    int T = blockIdx.x;
    float4 pf[8];
    if (T < n_tiles) {  // prefetch first tile
#pragma unroll
        for (int i = 0; i < 8; ++i) {
            int node = T * 64 + srow[i];
            if (node > n_nodes - 1) node = n_nodes - 1;  // clamp; never stored
            pf[i] = *(const float4*)(X + (size_t)node * EMBED + scol[i]);
        }
    }

    for (; T < n_tiles; T += gridDim.x) {
        const int mblk = T * 64;

        // Stage: spill prefetched registers to LDS (convert f32->f16 once).
#pragma unroll
        for (int i = 0; i < 8; ++i) {
            half4 h;
            h[0] = (_Float16)pf[i].x; h[1] = (_Float16)pf[i].y;
            h[2] = (_Float16)pf[i].z; h[3] = (_Float16)pf[i].w;
            *(half4*)(xs + srow[i] * 136 + scol[i]) = h;
        }
        __syncthreads();  // S1: stage visible

        // Prefetch next tile NOW — loads overlap this tile's MFMA+epilogue.
        const int Tn = T + gridDim.x;
        if (Tn < n_tiles) {
#pragma unroll
            for (int i = 0; i < 8; ++i) {
                int node = Tn * 64 + srow[i];
                if (node > n_nodes - 1) node = n_nodes - 1;
                pf[i] = *(const float4*)(X + (size_t)node * EMBED + scol[i]);
            }
        }

        floatx4 acc[4][4];  // [mf: node tile][jf: col tile]
#pragma unroll
        for (int a = 0; a < 4; ++a)
#pragma unroll
            for (int b = 0; b < 4; ++b)
                acc[a][b] = (floatx4){0.f, 0.f, 0.f, 0.f};

#pragma unroll
        for (int ks = 0; ks < 4; ++ks) {
            const int k0 = ks * 32 + quad * 8;
            half8 xf[4];  // B-operand: B[k][n=lane&15] = Xf16[node mf*16+lm][k]
#pragma unroll
            for (int mf = 0; mf < 4; ++mf)
                xf[mf] = *(const half8*)(xs + (mf * 16 + lm) * 136 + k0);
#pragma unroll
            for (int jf = 0; jf < 4; ++jf) {
                const int j = w * 64 + jf * 16 + lm;  // A-op: WT row = out col
                const half8 wf = *(const half8*)(WT + (size_t)j * EMBED + k0);
#pragma unroll
                for (int mf = 0; mf < 4; ++mf)
                    acc[mf][jf] = __builtin_amdgcn_mfma_f32_16x16x32_f16(wf, xf[mf], acc[mf][jf], 0, 0, 0);
            }
        }
        __syncthreads();  // S2: xs reads done before outs overwrites union

        // Pack D into LDS out tile: node-major [local node][j], stride 264.
        // D: col(lane&15) = node within mf-tile, row(quad*4+r) = output col j.
#pragma unroll
        for (int mf = 0; mf < 4; ++mf) {
#pragma unroll
            for (int jf = 0; jf < 4; ++jf) {
                half4 h;
#pragma unroll
                for (int r = 0; r < 4; ++r) h[r] = (_Float16)acc[mf][jf][r];
                *(half4*)(outs + (mf * 16 + lm) * 264 + w * 64 + jf * 16 + quad * 4) = h;
            }
        }
        __syncthreads();  // S3: outs visible

        // Coalesced store: 64 nodes x 512 B contiguous in AB (node-major).
#pragma unroll
        for (int i = 0; i < 8; ++i) {
            const int idx8 = i * 256 + t;         // half8 index in 64x256 tile
            const int node = idx8 >> 5, jj = idx8 & 31;
            if (mblk + node < n_nodes)
                *(half8*)(AB + (size_t)(mblk + node) * 256 + jj * 8) =
                    *(const half8*)(outs + node * 264 + jj * 8);
        }
        __syncthreads();  // S4: outs reads done before next tile's stage
    }
}

// --- Kernel 2: per-edge MLP. 16 edges per wave-group, persistent waves,
// 2-deep software pipeline with sched_barrier(0) pins: while computing
// group g (set A), group g+1's 8 gathers (set B) and group g+2's indices
// are REQUIRED to be issued (the barrier forbids sinking them below the
// comp reads). Issue order idx -> gathers -> comp gives counted vmcnt
// waits (vmcnt(10)) with no full drain in steady state.
__global__ __launch_bounds__(256, 3) void edge_mlp(
    const _Float16* __restrict__ AB, const int* __restrict__ eidx,
    const int* __restrict__ flag, const _Float16* __restrict__ b1f,
    const _Float16* __restrict__ W2PT, const float* __restrict__ b2,
    float* __restrict__ out, int n_edges) {
    const int lane = threadIdx.x & 63, lm = lane & 15, quad = lane >> 4;
    const int W = gridDim.x * 4;               // total waves
    const int G = (n_edges + 15) / 16;         // 16-edge groups
    const int wid = blockIdx.x * 4 + (threadIdx.x >> 6);
    if (wid >= G) return;

    const int mode = *flag;        // wave-uniform
    const float b2v = b2[lm & 1];  // only used when lm<2

    // Loop-invariant operands in registers (kept out of the vmcnt stream).
    half8 wv[4], bv[4];
#pragma unroll
    for (int ks = 0; ks < 4; ++ks) {
        wv[ks] = *(const half8*)(W2PT + lm * 128 + ks * 32 + quad * 8);
        bv[ks] = *(const half8*)(b1f + ks * 32 + quad * 8);
    }

    // Lane lm serves edge g*16+lm (quads replicate -> broadcast loads).
    auto ldidx = [&](int g, int& r, int& c) {
        int e = g * 16 + lm;
        if (e > n_edges - 1) e = n_edges - 1;  // tail clamp; stores guarded
        if (mode) {  // int64 layout: low word at int32 index 2*k
            r = eidx[2 * (size_t)e];
            c = eidx[2 * ((size_t)n_edges + e)];
        } else {
            r = eidx[e];
            c = eidx[(size_t)n_edges + e];
        }
    };

    // Issue the 8 gathers for one group (each b128: 16 edges x one 64B line).
    auto gather = [&](int r, int c, half8* d) {
        const _Float16* ap = AB + (size_t)r * 256;
        const _Float16* bp = AB + (size_t)c * 256 + 128;
#pragma unroll
        for (int ks = 0; ks < 4; ++ks) {
            const int k0 = ks * 32 + quad * 8;
            d[ks]     = *(const half8*)(ap + k0);
            d[ks + 4] = *(const half8*)(bp + k0);
        }
    };

    auto comp = [&](int g, const half8* d) {
        floatx4 acc = (floatx4){0.f, 0.f, 0.f, 0.f};
#pragma unroll
        for (int ks = 0; ks < 4; ++ks) {
            half8 h = d[ks] + d[ks + 4] + bv[ks];
#pragma unroll
            for (int j = 0; j < 8; ++j)
                h[j] = h[j] > (_Float16)0.f ? h[j] : (_Float16)0.f;
            acc = __builtin_amdgcn_mfma_f32_16x16x32_f16(h, wv[ks], acc, 0, 0, 0);
        }
        if (lm < 2) {
            const int eb = g * 16;
#pragma unroll
            for (int r = 0; r < 4; ++r) {
                const int ed = eb + quad * 4 + r;
                if (ed < n_edges) out[(size_t)ed * 2 + lm] = acc[r] + b2v;
            }
        }
    };

    // ---- pipeline prologue ----
    int g0 = wid;
    int g1 = g0 + W;
    bool h1 = g1 < G;
    int r0, c0, r1, c1;
    ldidx(g0, r0, c0);                 // 2 vm
    if (h1) ldidx(g1, r1, c1);         // 2 vm
    half8 a0[8], a1[8];
    gather(r0, c0, a0);                // 8 vm in flight for g0
    __builtin_amdgcn_sched_barrier(0); // pin: gather0 issued before loop body

    // ---- steady state: two phases per iteration, static register names ----
    for (;;) {
        // Phase 0: a0 outstanding for g0; idx(g1) in regs.
        const int g2 = g1 + W;
        const bool h2 = h1 && (g2 < G);
        if (h1) {
            if (h2) ldidx(g2, r0, c0);      // reuse r0/c0 regs for g2
            __builtin_amdgcn_sched_barrier(0);
            gather(r1, c1, a1);             // a0 stays outstanding
            __builtin_amdgcn_sched_barrier(0);  // forbid sinking below comp
        }
        comp(g0, a0);                        // wait a0 = vmcnt(10)
        if (!h1) break;

        // Phase 1: roles swapped — a1 outstanding for g1; idx(g2) in regs.
        const int g3 = g2 + W;
        const bool h3 = h2 && (g3 < G);
        if (h2) {
            if (h3) ldidx(g3, r1, c1);
            __builtin_amdgcn_sched_barrier(0);
            gather(r0, c0, a0);
            __builtin_amdgcn_sched_barrier(0);
        }
        comp(g1, a1);                        // wait a1 = vmcnt(10)
        if (!h2) break;

        g0 = g2; g1 = g3; h1 = h3;
    }
}

extern "C" void kernel_launch(void* const* d_in, const int* in_sizes, int n_in,
                              void* d_out, int out_size, void* d_ws, size_t ws_size,
                              hipStream_t stream) {
    const float* X   = (const float*)d_in[0];
    const int*   idx = (const int*)d_in[1];
    const float* W1  = (const float*)d_in[2];
    const float* b1  = (const float*)d_in[3];
    const float* W2  = (const float*)d_in[4];
    const float* b2  = (const float*)d_in[5];
    float* out = (float*)d_out;

    const int n_nodes = in_sizes[0] / EMBED;   // 100000
    const int n_edges = in_sizes[1] / 2;       // 500000

    // ws: flag @0 | AB @256 (n_nodes*256*2 B) | WT (64KB) | W2PT (4KB) | b1f (256B)
    char* ws = (char*)d_ws;
    int*      flag = (int*)ws;
    _Float16* AB   = (_Float16*)(ws + 256);
    _Float16* WT   = (_Float16*)(ws + 256 + (size_t)n_nodes * 512);
    _Float16* W2PT = WT + 256 * 128;
    _Float16* b1f  = W2PT + 16 * 128;

    const int n_tiles = (n_nodes + 63) / 64;   // 1563

    prep<<<129, 256, 0, stream>>>(W1, W2, b1, idx, WT, W2PT, b1f, flag);
    gemm_ab<<<782, 256, 0, stream>>>(X, WT, AB, n_nodes, n_tiles);
    // 768 persistent blocks = 3 blocks/CU x 4 waves = 12 waves/CU at the
    // (256,3) VGPR cap; ~10 groups/wave keeps the 2-deep pipeline filled.
    edge_mlp<<<768, 256, 0, stream>>>(
        AB, idx, flag, b1f, W2PT, b2, out, n_edges);
}